// Round 1
// baseline (710.098 us; speedup 1.0000x reference)
//
#include <hip/hip_runtime.h>

#define NT 8192       // tokens
#define NJ 24         // joints
#define DD 256        // per-joint dim
#define NH 8          // heads
#define FF 32         // head dim
#define C3 768        // q(256) + k(256) + v(256)

typedef __attribute__((ext_vector_type(8))) short bf16x8;
typedef __attribute__((ext_vector_type(4))) float f32x4;

__device__ __forceinline__ unsigned short f2bf(float f) {
    union { float f; unsigned int u; } c; c.f = f;
    unsigned int u = c.u;
    unsigned int r = (u + 0x7fffu + ((u >> 16) & 1u)) >> 16;
    return (unsigned short)r;
}
__device__ __forceinline__ float bf2f(unsigned short h) {
    union { unsigned int u; float f; } c; c.u = ((unsigned int)h) << 16;
    return c.f;
}
__device__ __forceinline__ float u2f(unsigned int u) {
    union { unsigned int u; float f; } c; c.u = u;
    return c.f;
}
// unpack 8 bf16 (one uint4) -> 8 floats. elem0 = low ushort of .x
__device__ __forceinline__ void up8(uint4 w, float* f) {
    f[0] = u2f(w.x << 16); f[1] = u2f(w.x & 0xffff0000u);
    f[2] = u2f(w.y << 16); f[3] = u2f(w.y & 0xffff0000u);
    f[4] = u2f(w.z << 16); f[5] = u2f(w.z & 0xffff0000u);
    f[6] = u2f(w.w << 16); f[7] = u2f(w.w & 0xffff0000u);
}

// ---------------- pack kernels ----------------
__global__ void pack_w(const float* __restrict__ Wq, const float* __restrict__ Wk,
                       const float* __restrict__ Wv, unsigned short* __restrict__ wbt) {
    size_t idx = (size_t)blockIdx.x * 256 + threadIdx.x;
    const size_t total = (size_t)NJ * C3 * DD;
    if (idx >= total) return;
    int d = idx & 255;
    int rest = (int)(idx >> 8);
    int c = rest % C3;
    int n = rest / C3;
    float v;
    if (c < 256) {
        int h = c >> 5, f = c & 31;
        v = Wq[((((size_t)h * NJ + n) * DD) + d) * FF + f];
    } else if (c < 512) {
        int cc = c - 256; int h = cc >> 5, f = cc & 31;
        v = Wk[(((size_t)h * DD) + d) * FF + f];
    } else {
        int cc = c - 512; int h = cc >> 5, f = cc & 31;
        v = Wv[(((size_t)h * DD) + d) * FF + f];
    }
    wbt[idx] = f2bf(v);
}

__global__ void pack_b(const float* __restrict__ bq, const float* __restrict__ bk,
                       const float* __restrict__ bv, float* __restrict__ bias) {
    int idx = blockIdx.x * 256 + threadIdx.x;   // NJ*C3 = 18432
    if (idx >= NJ * C3) return;
    int c = idx % C3;
    int n = idx / C3;
    float v;
    if (c < 256) {
        int h = c >> 5, f = c & 31;
        v = bq[((h * NJ + n) * FF) + f];
    } else if (c < 512) {
        int cc = c - 256; int h = cc >> 5, f = cc & 31;
        v = bk[h * FF + f];
    } else {
        int cc = c - 512; int h = cc >> 5, f = cc & 31;
        v = bv[h * FF + f];
    }
    bias[idx] = v;
}

// x fp32 -> bf16 (xb), one pass
__global__ void pack_x(const float* __restrict__ x, unsigned short* __restrict__ xb) {
    size_t idx = (size_t)blockIdx.x * 256 + threadIdx.x;   // one float4 each
    const size_t total = (size_t)NT * NJ * DD / 4;
    if (idx >= total) return;
    float4 v = ((const float4*)x)[idx];
    ushort4 h;
    h.x = f2bf(v.x); h.y = f2bf(v.y); h.z = f2bf(v.z); h.w = f2bf(v.w);
    ((ushort4*)xb)[idx] = h;
}

// ---------------- QKV projection GEMM ----------------
// per joint n: C(chunk x 768) = A(chunk x 256) @ B(256 x 768), bf16 MFMA, 128x128 tile
#define BM 128
#define BN 128
#define LDSP 72   // padded LDS row stride in bf16 (64 + 8): stride 144 B -> 2-way (free)

__global__ __launch_bounds__(256, 2)
void gemm_qkv(const unsigned short* __restrict__ xb, const unsigned short* __restrict__ wbt,
              const float* __restrict__ bias, unsigned short* __restrict__ qkv,
              int t0) {
    const int nb = blockIdx.x;   // 0..5   col block
    const int mb = blockIdx.y;   // row (token) block within chunk
    const int nj = blockIdx.z;   // joint
    const int tid = threadIdx.x;
    const int wave = tid >> 6, lane = tid & 63;

    __shared__ unsigned short As[BM * LDSP];
    __shared__ unsigned short Bs[BN * LDSP];

    f32x4 acc[4][4];
    #pragma unroll
    for (int i = 0; i < 4; ++i)
        #pragma unroll
        for (int j = 0; j < 4; ++j)
            #pragma unroll
            for (int r = 0; r < 4; ++r) acc[i][j][r] = 0.f;

    const int trow0 = t0 + mb * BM;
    const unsigned short* xA = xb + (size_t)trow0 * (NJ * DD) + nj * DD;
    const unsigned short* wB = wbt + ((size_t)nj * C3 + (size_t)nb * BN) * DD;

    for (int kb = 0; kb < 4; ++kb) {
        // stage A: 128 tokens x 64 d, bf16, 16B chunks
        {
            const unsigned short* src = xA + kb * 64;
            #pragma unroll
            for (int j = 0; j < 4; ++j) {
                int q = tid + j * 256;        // 0..1023
                int row = q >> 3;             // 8 x 16B chunks per row
                int c8 = (q & 7) * 8;
                int4 v = *(const int4*)(src + (size_t)row * (NJ * DD) + c8);
                *(int4*)&As[row * LDSP + c8] = v;
            }
        }
        // stage B: 128 cols(c) x 64 d, bf16 pre-transposed
        {
            const unsigned short* src = wB + kb * 64;
            #pragma unroll
            for (int j = 0; j < 4; ++j) {
                int q = tid + j * 256;        // 0..1023
                int row = q >> 3;
                int c8 = (q & 7) * 8;
                int4 v = *(const int4*)(src + (size_t)row * DD + c8);
                *(int4*)&Bs[row * LDSP + c8] = v;
            }
        }
        __syncthreads();
        const int wr = (wave >> 1) * 64;
        const int wc = (wave & 1) * 64;
        const int lr = lane & 15;
        const int kq = (lane >> 4) * 8;
        #pragma unroll
        for (int kk = 0; kk < 2; ++kk) {
            bf16x8 a[4], b[4];
            #pragma unroll
            for (int i = 0; i < 4; ++i)
                a[i] = *(const bf16x8*)&As[(wr + i * 16 + lr) * LDSP + kk * 32 + kq];
            #pragma unroll
            for (int j = 0; j < 4; ++j)
                b[j] = *(const bf16x8*)&Bs[(wc + j * 16 + lr) * LDSP + kk * 32 + kq];
            #pragma unroll
            for (int i = 0; i < 4; ++i)
                #pragma unroll
                for (int j = 0; j < 4; ++j)
                    acc[i][j] = __builtin_amdgcn_mfma_f32_16x16x32_bf16(a[i], b[j], acc[i][j], 0, 0, 0);
        }
        __syncthreads();
    }

    // epilogue: C/D layout col=lane&15, row=(lane>>4)*4+reg
    const int wr = (wave >> 1) * 64;
    const int wc = (wave & 1) * 64;
    const int ln = lane & 15;
    const int lq = (lane >> 4) * 4;
    float bv[4];
    #pragma unroll
    for (int j = 0; j < 4; ++j)
        bv[j] = bias[nj * C3 + nb * BN + wc + j * 16 + ln];
    #pragma unroll
    for (int i = 0; i < 4; ++i) {
        #pragma unroll
        for (int r = 0; r < 4; ++r) {
            int trow = mb * BM + wr + i * 16 + lq + r;   // local within chunk
            size_t base = ((size_t)trow * NJ + nj) * C3 + (size_t)nb * BN;
            #pragma unroll
            for (int j = 0; j < 4; ++j) {
                float val = acc[i][j][r] + bv[j];
                qkv[base + wc + j * 16 + ln] = f2bf(val);
            }
        }
    }
}

// ---------------- attention + residual + LayerNorm ----------------
// K/V unpacked ONCE per token to fp32 LDS (shared across the 24 n-threads of a
// head via broadcast ds_read_b128); Q read per-thread from global (private).
// All m-loops fully unrolled so s[]/o[]/qf[] are statically indexed (VGPRs).
__global__ __launch_bounds__(256, 3)
void attn_ln(const unsigned short* __restrict__ qkv, const float* __restrict__ x,
             const float* __restrict__ gamma, const float* __restrict__ beta,
             float* __restrict__ out, int t0) {
    const int tloc = blockIdx.x;
    const int t = t0 + tloc;
    const int tid = threadIdx.x;
    const int wave = tid >> 6, lane = tid & 63;

    // kbuf: fp32 K [h][m][f] 24576 B ; vbuf: fp32 V 24576 B.
    // kbuf is reused as the fp32 attention-output buffer (needs exactly 24576 B).
    // 49.2 KB LDS -> 3 blocks/CU (launch_bounds(256,3): VGPR cap ~170).
    __shared__ __align__(16) float kbuf[NH * NJ * FF];
    __shared__ __align__(16) float vbuf[NH * NJ * FF];
    __shared__ float red[8];
    __shared__ float stats[2];
    float* os = kbuf;

    // ---- stage K,V -> fp32 LDS (K|V region per joint = shorts [m*C3+256, m*C3+768)) ----
    {
        const uint4* src = (const uint4*)(qkv + (size_t)tloc * NJ * C3);
        #pragma unroll
        for (int j = 0; j < 6; ++j) {
            int idx = tid + j * 256;          // 0..1535 (24 joints x 64 uint4)
            int m = idx >> 6;
            int r = idx & 63;
            uint4 w = src[m * (C3 / 8) + 32 + r];
            float f[8]; up8(w, f);
            int c = r * 8;                    // 0..504 within [K|V] 512-short region
            int cc = c & 255;
            int h = cc >> 5, f0 = cc & 31;
            float* dst = ((c & 256) ? vbuf : kbuf) + ((h * NJ + m) * FF + f0);
            *(float4*)dst       = make_float4(f[0], f[1], f[2], f[3]);
            *(float4*)(dst + 4) = make_float4(f[4], f[5], f[6], f[7]);
        }
    }

    // ---- load this thread's q from global (bf16, L2/L3-resident) ----
    float qf[FF];
    const bool active = tid < NH * NJ;
    int hn = 0, nn = 0;
    if (active) {
        const int h = tid / NJ;
        const int n = tid - h * NJ;
        hn = h; nn = n;
        const uint4* qp = (const uint4*)(qkv + (size_t)tloc * NJ * C3 + n * C3 + h * FF);
        #pragma unroll
        for (int jj = 0; jj < 4; ++jj) { uint4 w = qp[jj]; up8(w, &qf[jj * 8]); }
    }
    __syncthreads();

    float o[FF];
    if (active) {
        const float* Kh = kbuf + hn * (NJ * FF);
        const float* Vh = vbuf + hn * (NJ * FF);
        float s[NJ];
        float mx = -1e30f;
        #pragma unroll
        for (int m = 0; m < NJ; ++m) {
            const float4* kp = (const float4*)(Kh + m * FF);
            float a = 0.f;
            #pragma unroll
            for (int jj = 0; jj < 8; ++jj) {
                float4 k4 = kp[jj];
                a += qf[jj * 4 + 0] * k4.x + qf[jj * 4 + 1] * k4.y
                   + qf[jj * 4 + 2] * k4.z + qf[jj * 4 + 3] * k4.w;
            }
            a *= 0.17677669529663687f;   // 1/sqrt(32)
            s[m] = a;
            mx = fmaxf(mx, a);
        }
        float sum = 0.f;
        #pragma unroll
        for (int m = 0; m < NJ; ++m) { s[m] = __expf(s[m] - mx); sum += s[m]; }
        float inv = 1.f / sum;
        #pragma unroll
        for (int f = 0; f < FF; ++f) o[f] = 0.f;
        #pragma unroll
        for (int m = 0; m < NJ; ++m) {
            float w = s[m] * inv;
            const float4* vp = (const float4*)(Vh + m * FF);
            #pragma unroll
            for (int jj = 0; jj < 8; ++jj) {
                float4 v4 = vp[jj];
                o[jj * 4 + 0] += w * v4.x; o[jj * 4 + 1] += w * v4.y;
                o[jj * 4 + 2] += w * v4.z; o[jj * 4 + 3] += w * v4.w;
            }
        }
    }
    __syncthreads();   // all K/V reads done; safe to overwrite kbuf as os
    if (active) {
        float* dst = os + nn * DD + hn * FF;
        #pragma unroll
        for (int jj = 0; jj < 8; ++jj)
            *(float4*)(dst + jj * 4) = make_float4(o[jj * 4], o[jj * 4 + 1], o[jj * 4 + 2], o[jj * 4 + 3]);
    }
    __syncthreads();

    // ---- residual + LayerNorm over 6144, fp32 x (exact residual path) ----
    const float4* x4 = (const float4*)(x + (size_t)t * (NJ * DD));
    const float4* o4 = (const float4*)os;
    float4 yv[6];
    float sum = 0.f, sq = 0.f;
    #pragma unroll
    for (int j = 0; j < 6; ++j) {
        float4 a = x4[tid + j * 256];
        float4 b = o4[tid + j * 256];
        float4 y;
        y.x = a.x + b.x; y.y = a.y + b.y; y.z = a.z + b.z; y.w = a.w + b.w;
        yv[j] = y;
        sum += y.x + y.y + y.z + y.w;
        sq  += y.x * y.x + y.y * y.y + y.z * y.z + y.w * y.w;
    }
    #pragma unroll
    for (int off = 32; off > 0; off >>= 1) {
        sum += __shfl_down(sum, off);
        sq  += __shfl_down(sq, off);
    }
    if (lane == 0) { red[wave] = sum; red[4 + wave] = sq; }
    __syncthreads();
    if (tid == 0) {
        float s = red[0] + red[1] + red[2] + red[3];
        float q = red[4] + red[5] + red[6] + red[7];
        float mu = s * (1.f / 6144.f);
        float var = q * (1.f / 6144.f) - mu * mu;
        stats[0] = mu;
        stats[1] = rsqrtf(var + 1e-5f);
    }
    __syncthreads();
    const float mu = stats[0], rs = stats[1];
    const float4* g4 = (const float4*)gamma;
    const float4* b4 = (const float4*)beta;
    float4* out4 = (float4*)(out + (size_t)t * (NJ * DD));
    #pragma unroll
    for (int j = 0; j < 6; ++j) {
        float4 g = g4[tid + j * 256];
        float4 bb = b4[tid + j * 256];
        float4 y = yv[j];
        y.x = (y.x - mu) * rs * g.x + bb.x;
        y.y = (y.y - mu) * rs * g.y + bb.y;
        y.z = (y.z - mu) * rs * g.z + bb.z;
        y.w = (y.w - mu) * rs * g.w + bb.w;
        out4[tid + j * 256] = y;
    }
}

// ---------------- launch ----------------
extern "C" void kernel_launch(void* const* d_in, const int* in_sizes, int n_in,
                              void* d_out, int out_size, void* d_ws, size_t ws_size,
                              hipStream_t stream) {
    const float* x     = (const float*)d_in[0];
    const float* Wq    = (const float*)d_in[1];
    const float* bq    = (const float*)d_in[2];
    const float* Wk    = (const float*)d_in[3];
    const float* bk    = (const float*)d_in[4];
    const float* Wv    = (const float*)d_in[5];
    const float* bv    = (const float*)d_in[6];
    const float* gamma = (const float*)d_in[7];
    const float* beta  = (const float*)d_in[8];
    float* out = (float*)d_out;

    char* ws = (char*)d_ws;
    const size_t wbt_bytes  = (size_t)NJ * C3 * DD * 2;        // 9,437,184
    const size_t bias_bytes = (size_t)NJ * C3 * 4;             // 73,728
    const size_t xb_bytes   = (size_t)NT * NJ * DD * 2;        // 100,663,296
    unsigned short* wbt = (unsigned short*)ws;
    float* bias = (float*)(ws + wbt_bytes);
    unsigned short* xb  = (unsigned short*)(ws + wbt_bytes + bias_bytes);
    unsigned short* qkv = (unsigned short*)(ws + wbt_bytes + bias_bytes + xb_bytes);

    // chunk tokens so qkv scratch fits in remaining ws
    const size_t fixed = wbt_bytes + bias_bytes + xb_bytes;
    size_t avail = (ws_size > fixed) ? ws_size - fixed : 0;
    int chunk = NT;
    while (chunk > BM && (size_t)chunk * NJ * C3 * 2 > avail) chunk >>= 1;

    const size_t wtotal = (size_t)NJ * C3 * DD;
    pack_w<<<dim3((unsigned)((wtotal + 255) / 256)), dim3(256), 0, stream>>>(Wq, Wk, Wv, wbt);
    pack_b<<<dim3((NJ * C3 + 255) / 256), dim3(256), 0, stream>>>(bq, bk, bv, bias);
    const size_t xtotal4 = (size_t)NT * NJ * DD / 4;
    pack_x<<<dim3((unsigned)((xtotal4 + 255) / 256)), dim3(256), 0, stream>>>(x, xb);

    for (int t0 = 0; t0 < NT; t0 += chunk) {
        gemm_qkv<<<dim3(6, chunk / BM, NJ), dim3(256), 0, stream>>>(xb, wbt, bias, qkv, t0);
        attn_ln<<<dim3(chunk), dim3(256), 0, stream>>>(qkv, x, gamma, beta, out, t0);
    }
}

// Round 2
// 643.368 us; speedup vs baseline: 1.1037x; 1.1037x over previous
//
#include <hip/hip_runtime.h>

#define NT 8192       // tokens
#define NJ 24         // joints
#define DD 256        // per-joint dim
#define NH 8          // heads
#define FF 32         // head dim
#define C3 768        // q(256) + k(256) + v(256)

typedef __attribute__((ext_vector_type(8))) short bf16x8;
typedef __attribute__((ext_vector_type(4))) float f32x4;

__device__ __forceinline__ unsigned short f2bf(float f) {
    union { float f; unsigned int u; } c; c.f = f;
    unsigned int u = c.u;
    unsigned int r = (u + 0x7fffu + ((u >> 16) & 1u)) >> 16;
    return (unsigned short)r;
}
__device__ __forceinline__ float u2f(unsigned int u) {
    union { unsigned int u; float f; } c; c.u = u;
    return c.f;
}
// unpack 8 bf16 (one uint4) -> 8 floats. elem0 = low ushort of .x
__device__ __forceinline__ void up8(uint4 w, float* f) {
    f[0] = u2f(w.x << 16); f[1] = u2f(w.x & 0xffff0000u);
    f[2] = u2f(w.y << 16); f[3] = u2f(w.y & 0xffff0000u);
    f[4] = u2f(w.z << 16); f[5] = u2f(w.z & 0xffff0000u);
    f[6] = u2f(w.w << 16); f[7] = u2f(w.w & 0xffff0000u);
}

// async global->LDS, 16B per lane. LDS dest = base + lane*16 (wave-uniform base).
__device__ __forceinline__ void gload16(const void* g, void* l) {
    __builtin_amdgcn_global_load_lds(
        (const __attribute__((address_space(1))) unsigned int*)g,
        (__attribute__((address_space(3))) unsigned int*)l, 16, 0, 0);
}

// ---------------- pack kernels ----------------
__global__ void pack_w(const float* __restrict__ Wq, const float* __restrict__ Wk,
                       const float* __restrict__ Wv, unsigned short* __restrict__ wbt) {
    size_t idx = (size_t)blockIdx.x * 256 + threadIdx.x;
    const size_t total = (size_t)NJ * C3 * DD;
    if (idx >= total) return;
    int d = idx & 255;
    int rest = (int)(idx >> 8);
    int c = rest % C3;
    int n = rest / C3;
    float v;
    if (c < 256) {
        int h = c >> 5, f = c & 31;
        v = Wq[((((size_t)h * NJ + n) * DD) + d) * FF + f];
    } else if (c < 512) {
        int cc = c - 256; int h = cc >> 5, f = cc & 31;
        v = Wk[(((size_t)h * DD) + d) * FF + f];
    } else {
        int cc = c - 512; int h = cc >> 5, f = cc & 31;
        v = Wv[(((size_t)h * DD) + d) * FF + f];
    }
    wbt[idx] = f2bf(v);
}

__global__ void pack_b(const float* __restrict__ bq, const float* __restrict__ bk,
                       const float* __restrict__ bv, float* __restrict__ bias) {
    int idx = blockIdx.x * 256 + threadIdx.x;   // NJ*C3 = 18432
    if (idx >= NJ * C3) return;
    int c = idx % C3;
    int n = idx / C3;
    float v;
    if (c < 256) {
        int h = c >> 5, f = c & 31;
        v = bq[((h * NJ + n) * FF) + f];
    } else if (c < 512) {
        int cc = c - 256; int h = cc >> 5, f = cc & 31;
        v = bk[h * FF + f];
    } else {
        int cc = c - 512; int h = cc >> 5, f = cc & 31;
        v = bv[h * FF + f];
    }
    bias[idx] = v;
}

// x fp32 -> bf16 (xb), one pass
__global__ void pack_x(const float* __restrict__ x, unsigned short* __restrict__ xb) {
    size_t idx = (size_t)blockIdx.x * 256 + threadIdx.x;   // one float4 each
    const size_t total = (size_t)NT * NJ * DD / 4;
    if (idx >= total) return;
    float4 v = ((const float4*)x)[idx];
    ushort4 h;
    h.x = f2bf(v.x); h.y = f2bf(v.y); h.z = f2bf(v.z); h.w = f2bf(v.w);
    ((ushort4*)xb)[idx] = h;
}

// ---------------- QKV projection GEMM ----------------
// per joint n: C(chunk x 768) = A(chunk x 256) @ B(256 x 768), bf16 MFMA, 128x128 tile.
// m97 structure: global_load_lds width=16 into LINEAR [128][64] LDS with
// both-sides XOR swizzle (source col16 ^= row&7 at stage; read col16 ^= row&7).
#define BM 128
#define BN 128

__global__ __launch_bounds__(256, 3)
void gemm_qkv(const unsigned short* __restrict__ xb, const unsigned short* __restrict__ wbt,
              const float* __restrict__ bias, unsigned short* __restrict__ qkv,
              int t0, int mbs) {
    // XCD-chunked bijective swizzle: nwg = 144*mbs, always % 8 == 0.
    const int nwg = gridDim.x;
    const int cpx = nwg >> 3;
    const int bid = blockIdx.x;
    const int swz = (bid & 7) * cpx + (bid >> 3);
    const int nb = swz % 6;          // col block (0..5) — fastest: shares A-tile
    const int rest = swz / 6;
    const int mb = rest % mbs;       // token block
    const int nj = rest / mbs;       // joint

    const int tid = threadIdx.x;
    const int wave = tid >> 6, lane = tid & 63;

    __shared__ unsigned short As[BM * 64];   // 16 KB, swizzled content
    __shared__ unsigned short Bs[BN * 64];   // 16 KB

    f32x4 acc[4][4];
    #pragma unroll
    for (int i = 0; i < 4; ++i)
        #pragma unroll
        for (int j = 0; j < 4; ++j)
            #pragma unroll
            for (int r = 0; r < 4; ++r) acc[i][j][r] = 0.f;

    const int trow0 = t0 + mb * BM;
    const char* srcA = (const char*)(xb + (size_t)trow0 * (NJ * DD) + nj * DD);
    const char* srcB = (const char*)(wbt + ((size_t)nj * C3 + (size_t)nb * BN) * DD);

    const int rg = lane >> 3;            // row within 8-row group (0..7)
    const int sc = (lane & 7) ^ rg;      // pre-swizzled source 16B-column

    const int wr = (wave >> 1) * 64;
    const int wc = (wave & 1) * 64;
    const int lr = lane & 15;
    const int g  = lane >> 4;            // 0..3

    for (int kb = 0; kb < 4; ++kb) {
        // stage A: 4 instrs/wave, each 8 rows x 128B. src row stride 12288 B.
        #pragma unroll
        for (int i = 0; i < 4; ++i) {
            int row0 = wave * 32 + i * 8;
            gload16(srcA + (size_t)(row0 + rg) * (NJ * DD * 2) + kb * 128 + sc * 16,
                    (char*)As + row0 * 128);
        }
        // stage B: src row stride 512 B.
        #pragma unroll
        for (int i = 0; i < 4; ++i) {
            int row0 = wave * 32 + i * 8;
            gload16(srcB + (size_t)(row0 + rg) * (DD * 2) + kb * 128 + sc * 16,
                    (char*)Bs + row0 * 128);
        }
        __syncthreads();   // compiler drains vmcnt before barrier

        #pragma unroll
        for (int kk = 0; kk < 2; ++kk) {
            bf16x8 a[4], b[4];
            #pragma unroll
            for (int i = 0; i < 4; ++i) {
                int row = wr + i * 16 + lr;
                int c16 = (kk * 4 + g) ^ (row & 7);
                a[i] = *(const bf16x8*)((const char*)As + row * 128 + c16 * 16);
            }
            #pragma unroll
            for (int j = 0; j < 4; ++j) {
                int row = wc + j * 16 + lr;
                int c16 = (kk * 4 + g) ^ (row & 7);
                b[j] = *(const bf16x8*)((const char*)Bs + row * 128 + c16 * 16);
            }
            #pragma unroll
            for (int i = 0; i < 4; ++i)
                #pragma unroll
                for (int j = 0; j < 4; ++j)
                    acc[i][j] = __builtin_amdgcn_mfma_f32_16x16x32_bf16(a[i], b[j], acc[i][j], 0, 0, 0);
        }
        __syncthreads();
    }

    // epilogue: C/D layout col=lane&15, row=(lane>>4)*4+reg
    const int ln = lane & 15;
    const int lq = (lane >> 4) * 4;
    float bv[4];
    #pragma unroll
    for (int j = 0; j < 4; ++j)
        bv[j] = bias[nj * C3 + nb * BN + wc + j * 16 + ln];
    #pragma unroll
    for (int i = 0; i < 4; ++i) {
        #pragma unroll
        for (int r = 0; r < 4; ++r) {
            int trow = mb * BM + wr + i * 16 + lq + r;   // local within chunk
            size_t base = ((size_t)trow * NJ + nj) * C3 + (size_t)nb * BN;
            #pragma unroll
            for (int j = 0; j < 4; ++j) {
                float val = acc[i][j][r] + bv[j];
                qkv[base + wc + j * 16 + ln] = f2bf(val);
            }
        }
    }
}

// ---------------- attention + residual + LayerNorm ----------------
__global__ __launch_bounds__(256, 4)
void attn_ln(const unsigned short* __restrict__ qkv, const float* __restrict__ x,
             const float* __restrict__ gamma, const float* __restrict__ beta,
             float* __restrict__ out, int t0) {
    const int tloc = blockIdx.x;
    const int t = t0 + tloc;
    const int tid = threadIdx.x;
    const int wave = tid >> 6, lane = tid & 63;

    // qkv staged as bf16 (36864 B); after attention the SAME region is reused
    // as the fp32 attention-output buffer (24576 B) -> 37 KB LDS, 4 blocks/CU
    __shared__ __align__(16) char smem[NJ * C3 * 2];
    unsigned short* qs = (unsigned short*)smem;
    float* os = (float*)smem;
    __shared__ float red[8];
    __shared__ float stats[2];

    // load qkv for this token (2304 int4)
    {
        const int4* src = (const int4*)(qkv + (size_t)tloc * NJ * C3);
        int4* dst = (int4*)qs;
        #pragma unroll
        for (int j = 0; j < 9; ++j)
            dst[tid + j * 256] = src[tid + j * 256];
    }
    __syncthreads();

    float o[FF];
    const bool active = tid < NH * NJ;
    int hn = 0, nn = 0;
    if (active) {
        const int h = tid / NJ;
        const int n = tid - h * NJ;
        hn = h; nn = n;
        const int hb = h * FF;   // ushort offset within a joint row
        float qf[FF];
        {
            const uint4* qp = (const uint4*)(qs + n * C3 + hb);
            #pragma unroll
            for (int jj = 0; jj < 4; ++jj) { uint4 w = qp[jj]; up8(w, &qf[jj * 8]); }
        }
        float s[NJ];
        float mx = -1e30f;
        for (int m = 0; m < NJ; ++m) {
            const uint4* kp = (const uint4*)(qs + m * C3 + 256 + hb);
            float a = 0.f;
            #pragma unroll
            for (int jj = 0; jj < 4; ++jj) {
                uint4 w = kp[jj];
                float kf[8]; up8(w, kf);
                #pragma unroll
                for (int e = 0; e < 8; ++e) a += qf[jj * 8 + e] * kf[e];
            }
            a *= 0.17677669529663687f;   // 1/sqrt(32)
            s[m] = a;
            mx = fmaxf(mx, a);
        }
        float sum = 0.f;
        for (int m = 0; m < NJ; ++m) { s[m] = __expf(s[m] - mx); sum += s[m]; }
        float inv = 1.f / sum;
        #pragma unroll
        for (int f = 0; f < FF; ++f) o[f] = 0.f;
        for (int m = 0; m < NJ; ++m) {
            float w = s[m] * inv;
            const uint4* vp = (const uint4*)(qs + m * C3 + 512 + hb);
            #pragma unroll
            for (int jj = 0; jj < 4; ++jj) {
                uint4 wv = vp[jj];
                float vf[8]; up8(wv, vf);
                #pragma unroll
                for (int e = 0; e < 8; ++e) o[jj * 8 + e] += w * vf[e];
            }
        }
    }
    __syncthreads();   // all reads of qs done; safe to overwrite as os
    if (active) {
        float* dst = os + nn * DD + hn * FF;
        #pragma unroll
        for (int jj = 0; jj < 8; ++jj)
            *(float4*)(dst + jj * 4) = make_float4(o[jj * 4], o[jj * 4 + 1], o[jj * 4 + 2], o[jj * 4 + 3]);
    }
    __syncthreads();

    // residual + LayerNorm over 6144, fp32 x (exact residual path)
    const float4* x4 = (const float4*)(x + (size_t)t * (NJ * DD));
    const float4* o4 = (const float4*)os;
    float4 yv[6];
    float sum = 0.f, sq = 0.f;
    #pragma unroll
    for (int j = 0; j < 6; ++j) {
        float4 a = x4[tid + j * 256];
        float4 b = o4[tid + j * 256];
        float4 y;
        y.x = a.x + b.x; y.y = a.y + b.y; y.z = a.z + b.z; y.w = a.w + b.w;
        yv[j] = y;
        sum += y.x + y.y + y.z + y.w;
        sq  += y.x * y.x + y.y * y.y + y.z * y.z + y.w * y.w;
    }
    #pragma unroll
    for (int off = 32; off > 0; off >>= 1) {
        sum += __shfl_down(sum, off);
        sq  += __shfl_down(sq, off);
    }
    if (lane == 0) { red[wave] = sum; red[4 + wave] = sq; }
    __syncthreads();
    if (tid == 0) {
        float s = red[0] + red[1] + red[2] + red[3];
        float q = red[4] + red[5] + red[6] + red[7];
        float mu = s * (1.f / 6144.f);
        float var = q * (1.f / 6144.f) - mu * mu;
        stats[0] = mu;
        stats[1] = rsqrtf(var + 1e-5f);
    }
    __syncthreads();
    const float mu = stats[0], rs = stats[1];
    const float4* g4 = (const float4*)gamma;
    const float4* b4 = (const float4*)beta;
    float4* out4 = (float4*)(out + (size_t)t * (NJ * DD));
    #pragma unroll
    for (int j = 0; j < 6; ++j) {
        float4 g = g4[tid + j * 256];
        float4 bb = b4[tid + j * 256];
        float4 y = yv[j];
        y.x = (y.x - mu) * rs * g.x + bb.x;
        y.y = (y.y - mu) * rs * g.y + bb.y;
        y.z = (y.z - mu) * rs * g.z + bb.z;
        y.w = (y.w - mu) * rs * g.w + bb.w;
        out4[tid + j * 256] = y;
    }
}

// ---------------- launch ----------------
extern "C" void kernel_launch(void* const* d_in, const int* in_sizes, int n_in,
                              void* d_out, int out_size, void* d_ws, size_t ws_size,
                              hipStream_t stream) {
    const float* x     = (const float*)d_in[0];
    const float* Wq    = (const float*)d_in[1];
    const float* bq    = (const float*)d_in[2];
    const float* Wk    = (const float*)d_in[3];
    const float* bk    = (const float*)d_in[4];
    const float* Wv    = (const float*)d_in[5];
    const float* bv    = (const float*)d_in[6];
    const float* gamma = (const float*)d_in[7];
    const float* beta  = (const float*)d_in[8];
    float* out = (float*)d_out;

    char* ws = (char*)d_ws;
    const size_t wbt_bytes  = (size_t)NJ * C3 * DD * 2;        // 9,437,184
    const size_t bias_bytes = (size_t)NJ * C3 * 4;             // 73,728
    const size_t xb_bytes   = (size_t)NT * NJ * DD * 2;        // 100,663,296
    unsigned short* wbt = (unsigned short*)ws;
    float* bias = (float*)(ws + wbt_bytes);
    unsigned short* xb  = (unsigned short*)(ws + wbt_bytes + bias_bytes);
    unsigned short* qkv = (unsigned short*)(ws + wbt_bytes + bias_bytes + xb_bytes);

    // chunk tokens so qkv scratch fits in remaining ws
    const size_t fixed = wbt_bytes + bias_bytes + xb_bytes;
    size_t avail = (ws_size > fixed) ? ws_size - fixed : 0;
    int chunk = NT;
    while (chunk > BM && (size_t)chunk * NJ * C3 * 2 > avail) chunk >>= 1;

    const size_t wtotal = (size_t)NJ * C3 * DD;
    pack_w<<<dim3((unsigned)((wtotal + 255) / 256)), dim3(256), 0, stream>>>(Wq, Wk, Wv, wbt);
    pack_b<<<dim3((NJ * C3 + 255) / 256), dim3(256), 0, stream>>>(bq, bk, bv, bias);
    const size_t xtotal4 = (size_t)NT * NJ * DD / 4;
    pack_x<<<dim3((unsigned)((xtotal4 + 255) / 256)), dim3(256), 0, stream>>>(x, xb);

    for (int t0 = 0; t0 < NT; t0 += chunk) {
        int mbs = chunk / BM;
        gemm_qkv<<<dim3(6 * mbs * NJ), dim3(256), 0, stream>>>(xb, wbt, bias, qkv, t0, mbs);
        attn_ln<<<dim3(chunk), dim3(256), 0, stream>>>(qkv, x, gamma, beta, out, t0);
    }
}

// Round 4
// 620.064 us; speedup vs baseline: 1.1452x; 1.0376x over previous
//
#include <hip/hip_runtime.h>

#define NT 8192       // tokens
#define NJ 24         // joints
#define DD 256        // per-joint dim
#define NH 8          // heads
#define FF 32         // head dim
#define C3 768        // q(256) + k(256) + v(256)

typedef __attribute__((ext_vector_type(8))) _Float16 f16x8;
typedef __attribute__((ext_vector_type(2))) _Float16 half2v;
typedef __attribute__((ext_vector_type(4))) float f32x4;

__device__ __forceinline__ unsigned short f2h(float f) {
    union { _Float16 h; unsigned short u; } c;
    c.h = (_Float16)f;
    return c.u;
}

// fused dot2: a,b are packed f16 pairs (as uint), f32 accumulate
__device__ __forceinline__ float dot2(unsigned int a, unsigned int b, float c) {
#if __has_builtin(__builtin_amdgcn_fdot2)
    return __builtin_amdgcn_fdot2(__builtin_bit_cast(half2v, a),
                                  __builtin_bit_cast(half2v, b), c, false);
#else
    half2v ha = __builtin_bit_cast(half2v, a);
    half2v hb = __builtin_bit_cast(half2v, b);
    return c + (float)ha[0] * (float)hb[0] + (float)ha[1] * (float)hb[1];
#endif
}

// async global->LDS, 16B per lane. LDS dest = base + lane*16 (wave-uniform base).
__device__ __forceinline__ void gload16(const void* g, void* l) {
    __builtin_amdgcn_global_load_lds(
        (const __attribute__((address_space(1))) unsigned int*)g,
        (__attribute__((address_space(3))) unsigned int*)l, 16, 0, 0);
}

// ---------------- pack kernels ----------------
__global__ void pack_w(const float* __restrict__ Wq, const float* __restrict__ Wk,
                       const float* __restrict__ Wv, unsigned short* __restrict__ wbt) {
    size_t idx = (size_t)blockIdx.x * 256 + threadIdx.x;
    const size_t total = (size_t)NJ * C3 * DD;
    if (idx >= total) return;
    int d = idx & 255;
    int rest = (int)(idx >> 8);
    int c = rest % C3;
    int n = rest / C3;
    float v;
    if (c < 256) {
        int h = c >> 5, f = c & 31;
        v = Wq[((((size_t)h * NJ + n) * DD) + d) * FF + f];
    } else if (c < 512) {
        int cc = c - 256; int h = cc >> 5, f = cc & 31;
        v = Wk[(((size_t)h * DD) + d) * FF + f];
    } else {
        int cc = c - 512; int h = cc >> 5, f = cc & 31;
        v = Wv[(((size_t)h * DD) + d) * FF + f];
    }
    wbt[idx] = f2h(v);
}

__global__ void pack_b(const float* __restrict__ bq, const float* __restrict__ bk,
                       const float* __restrict__ bv, float* __restrict__ bias) {
    int idx = blockIdx.x * 256 + threadIdx.x;   // NJ*C3 = 18432
    if (idx >= NJ * C3) return;
    int c = idx % C3;
    int n = idx / C3;
    float v;
    if (c < 256) {
        int h = c >> 5, f = c & 31;
        v = bq[((h * NJ + n) * FF) + f];
    } else if (c < 512) {
        int cc = c - 256; int h = cc >> 5, f = cc & 31;
        v = bk[h * FF + f];
    } else {
        int cc = c - 512; int h = cc >> 5, f = cc & 31;
        v = bv[h * FF + f];
    }
    bias[idx] = v;
}

// x fp32 -> f16 (xb), one pass
__global__ void pack_x(const float* __restrict__ x, unsigned short* __restrict__ xb) {
    size_t idx = (size_t)blockIdx.x * 256 + threadIdx.x;   // one float4 each
    const size_t total = (size_t)NT * NJ * DD / 4;
    if (idx >= total) return;
    float4 v = ((const float4*)x)[idx];
    ushort4 h;
    h.x = f2h(v.x); h.y = f2h(v.y); h.z = f2h(v.z); h.w = f2h(v.w);
    ((ushort4*)xb)[idx] = h;
}

// ---------------- QKV projection GEMM ----------------
// per joint n: C(chunk x 768) = A(chunk x 256) @ B(256 x 768), f16 MFMA, 128x128 tile.
// m97 structure: global_load_lds width=16 into LINEAR [128][64] LDS with
// both-sides XOR swizzle (source col16 ^= row&7 at stage; read col16 ^= row&7).
#define BM 128
#define BN 128

__global__ __launch_bounds__(256, 3)
void gemm_qkv(const unsigned short* __restrict__ xb, const unsigned short* __restrict__ wbt,
              const float* __restrict__ bias, unsigned short* __restrict__ qkv,
              int t0, int mbs) {
    // XCD-chunked bijective swizzle: nwg = 144*mbs, always % 8 == 0.
    const int nwg = gridDim.x;
    const int cpx = nwg >> 3;
    const int bid = blockIdx.x;
    const int swz = (bid & 7) * cpx + (bid >> 3);
    const int nb = swz % 6;          // col block (0..5) — fastest: shares A-tile
    const int rest = swz / 6;
    const int mb = rest % mbs;       // token block
    const int nj = rest / mbs;       // joint

    const int tid = threadIdx.x;
    const int wave = tid >> 6, lane = tid & 63;

    __shared__ unsigned short As[BM * 64];   // 16 KB, swizzled content
    __shared__ unsigned short Bs[BN * 64];   // 16 KB

    f32x4 acc[4][4];
    #pragma unroll
    for (int i = 0; i < 4; ++i)
        #pragma unroll
        for (int j = 0; j < 4; ++j)
            #pragma unroll
            for (int r = 0; r < 4; ++r) acc[i][j][r] = 0.f;

    const int trow0 = t0 + mb * BM;
    const char* srcA = (const char*)(xb + (size_t)trow0 * (NJ * DD) + nj * DD);
    const char* srcB = (const char*)(wbt + ((size_t)nj * C3 + (size_t)nb * BN) * DD);

    const int rg = lane >> 3;            // row within 8-row group (0..7)
    const int sc = (lane & 7) ^ rg;      // pre-swizzled source 16B-column

    const int wr = (wave >> 1) * 64;
    const int wc = (wave & 1) * 64;
    const int lr = lane & 15;
    const int g  = lane >> 4;            // 0..3

    for (int kb = 0; kb < 4; ++kb) {
        // stage A: 4 instrs/wave, each 8 rows x 128B. src row stride 12288 B.
        #pragma unroll
        for (int i = 0; i < 4; ++i) {
            int row0 = wave * 32 + i * 8;
            gload16(srcA + (size_t)(row0 + rg) * (NJ * DD * 2) + kb * 128 + sc * 16,
                    (char*)As + row0 * 128);
        }
        // stage B: src row stride 512 B.
        #pragma unroll
        for (int i = 0; i < 4; ++i) {
            int row0 = wave * 32 + i * 8;
            gload16(srcB + (size_t)(row0 + rg) * (DD * 2) + kb * 128 + sc * 16,
                    (char*)Bs + row0 * 128);
        }
        __syncthreads();   // compiler drains vmcnt before barrier

        #pragma unroll
        for (int kk = 0; kk < 2; ++kk) {
            f16x8 a[4], b[4];
            #pragma unroll
            for (int i = 0; i < 4; ++i) {
                int row = wr + i * 16 + lr;
                int c16 = (kk * 4 + g) ^ (row & 7);
                a[i] = *(const f16x8*)((const char*)As + row * 128 + c16 * 16);
            }
            #pragma unroll
            for (int j = 0; j < 4; ++j) {
                int row = wc + j * 16 + lr;
                int c16 = (kk * 4 + g) ^ (row & 7);
                b[j] = *(const f16x8*)((const char*)Bs + row * 128 + c16 * 16);
            }
            #pragma unroll
            for (int i = 0; i < 4; ++i)
                #pragma unroll
                for (int j = 0; j < 4; ++j)
                    acc[i][j] = __builtin_amdgcn_mfma_f32_16x16x32_f16(a[i], b[j], acc[i][j], 0, 0, 0);
        }
        __syncthreads();
    }

    // epilogue: C/D layout col=lane&15, row=(lane>>4)*4+reg
    const int ln = lane & 15;
    const int lq = (lane >> 4) * 4;
    float bv[4];
    #pragma unroll
    for (int j = 0; j < 4; ++j)
        bv[j] = bias[nj * C3 + nb * BN + wc + j * 16 + ln];
    #pragma unroll
    for (int i = 0; i < 4; ++i) {
        #pragma unroll
        for (int r = 0; r < 4; ++r) {
            int trow = mb * BM + wr + i * 16 + lq + r;   // local within chunk
            size_t base = ((size_t)trow * NJ + nj) * C3 + (size_t)nb * BN;
            #pragma unroll
            for (int j = 0; j < 4; ++j) {
                float val = acc[i][j][r] + bv[j];
                qkv[base + wc + j * 16 + ln] = f2h(val);
            }
        }
    }
}

// ---------------- attention + residual + LayerNorm ----------------
// f16 qkv. QK via v_dot2_f32_f16 (no unpack), PV via v_pk_fma_f16 (half2
// accumulate, <=24 terms). K+V staged to LDS (24.6 KB); Q per-thread from
// global. os (fp32 attn out) reuses the KV region, XOR-swizzled to break the
// same-bank scatter-write.
__global__ __launch_bounds__(256, 4)
void attn_ln(const unsigned short* __restrict__ qkv, const float* __restrict__ x,
             const float* __restrict__ gamma, const float* __restrict__ beta,
             float* __restrict__ out, int t0) {
    const int tloc = blockIdx.x;
    const int t = t0 + tloc;
    const int tid = threadIdx.x;
    const int wave = tid >> 6, lane = tid & 63;

    // kv[m][0..255] = K row (f16), kv[m][256..511] = V row (f16): 24576 B.
    // Reused after attention as fp32 os[6144] (exactly 24576 B).
    __shared__ __align__(16) unsigned short kv[NJ * 512];
    __shared__ float red[8];
    __shared__ float stats[2];
    float4* os4 = (float4*)kv;

    const uint4* tok = (const uint4*)(qkv + (size_t)tloc * (NJ * C3));

    // stage K+V: 1536 int4, 6 per thread, coalesced (per-m runs of 64 int4)
    #pragma unroll
    for (int j = 0; j < 6; ++j) {
        int idx = tid + j * 256;
        int m = idx >> 6, r = idx & 63;
        ((uint4*)kv)[(m << 6) + r] = tok[m * 96 + 32 + r];
    }

    // q for this thread from global (L2/L3-hot, private)
    const bool active = tid < NH * NJ;
    const int h = active ? (tid / NJ) : 0;
    const int n = active ? (tid - h * NJ) : 0;
    unsigned int qp[16];
    if (active) {
        const uint4* qsrc = tok + n * 96 + h * 4;
        #pragma unroll
        for (int jj = 0; jj < 4; ++jj) {
            uint4 w = qsrc[jj];
            qp[jj * 4 + 0] = w.x; qp[jj * 4 + 1] = w.y;
            qp[jj * 4 + 2] = w.z; qp[jj * 4 + 3] = w.w;
        }
    }
    __syncthreads();

    half2v o2[16];
    if (active) {
        const unsigned short* kbase = kv + h * FF;
        float s[NJ];
        float mx = -1e30f;
        #pragma unroll
        for (int m = 0; m < NJ; ++m) {
            const uint4* kp = (const uint4*)(kbase + m * 512);
            float a = 0.f;
            #pragma unroll
            for (int jj = 0; jj < 4; ++jj) {
                uint4 kw = kp[jj];
                a = dot2(kw.x, qp[jj * 4 + 0], a);
                a = dot2(kw.y, qp[jj * 4 + 1], a);
                a = dot2(kw.z, qp[jj * 4 + 2], a);
                a = dot2(kw.w, qp[jj * 4 + 3], a);
            }
            a *= 0.17677669529663687f;   // 1/sqrt(32)
            s[m] = a;
            mx = fmaxf(mx, a);
        }
        float sum = 0.f;
        #pragma unroll
        for (int m = 0; m < NJ; ++m) { s[m] = __expf(s[m] - mx); sum += s[m]; }
        float inv = 1.f / sum;
        #pragma unroll
        for (int k = 0; k < 16; ++k) o2[k] = half2v{(_Float16)0.f, (_Float16)0.f};
        const unsigned short* vbase = kv + 256 + h * FF;
        #pragma unroll
        for (int m = 0; m < NJ; ++m) {
            float wm = s[m] * inv;
            half2v wv = __builtin_bit_cast(half2v, __builtin_amdgcn_cvt_pkrtz(wm, wm));
            const uint4* vp = (const uint4*)(vbase + m * 512);
            #pragma unroll
            for (int jj = 0; jj < 4; ++jj) {
                uint4 vw = vp[jj];
                o2[jj * 4 + 0] += __builtin_bit_cast(half2v, vw.x) * wv;
                o2[jj * 4 + 1] += __builtin_bit_cast(half2v, vw.y) * wv;
                o2[jj * 4 + 2] += __builtin_bit_cast(half2v, vw.z) * wv;
                o2[jj * 4 + 3] += __builtin_bit_cast(half2v, vw.w) * wv;
            }
        }
    }
    __syncthreads();   // all K/V reads done; safe to overwrite kv as os
    if (active) {
        // float4 index wi = n*64 + h*8 + jj, XOR-swizzled by row (n) to spread banks
        int base4 = n * 64 + h * 8;
        #pragma unroll
        for (int jj = 0; jj < 8; ++jj) {
            int wi = base4 + jj;
            int sw = wi ^ ((wi >> 6) & 7);
            os4[sw] = make_float4((float)o2[jj * 2][0], (float)o2[jj * 2][1],
                                  (float)o2[jj * 2 + 1][0], (float)o2[jj * 2 + 1][1]);
        }
    }
    __syncthreads();

    // residual + LayerNorm over 6144, fp32 x (exact residual path)
    const float4* x4 = (const float4*)(x + (size_t)t * (NJ * DD));
    float4 yv[6];
    float sum = 0.f, sq = 0.f;
    #pragma unroll
    for (int j = 0; j < 6; ++j) {
        int ri = tid + j * 256;
        float4 a = x4[ri];
        float4 b = os4[ri ^ ((ri >> 6) & 7)];
        float4 y;
        y.x = a.x + b.x; y.y = a.y + b.y; y.z = a.z + b.z; y.w = a.w + b.w;
        yv[j] = y;
        sum += y.x + y.y + y.z + y.w;
        sq  += y.x * y.x + y.y * y.y + y.z * y.z + y.w * y.w;
    }
    #pragma unroll
    for (int off = 32; off > 0; off >>= 1) {
        sum += __shfl_down(sum, off);
        sq  += __shfl_down(sq, off);
    }
    if (lane == 0) { red[wave] = sum; red[4 + wave] = sq; }
    __syncthreads();
    if (tid == 0) {
        float s = red[0] + red[1] + red[2] + red[3];
        float q = red[4] + red[5] + red[6] + red[7];
        float mu = s * (1.f / 6144.f);
        float var = q * (1.f / 6144.f) - mu * mu;
        stats[0] = mu;
        stats[1] = rsqrtf(var + 1e-5f);
    }
    __syncthreads();
    const float mu = stats[0], rs = stats[1];
    const float4* g4 = (const float4*)gamma;
    const float4* b4 = (const float4*)beta;
    float4* out4 = (float4*)(out + (size_t)t * (NJ * DD));
    #pragma unroll
    for (int j = 0; j < 6; ++j) {
        float4 g = g4[tid + j * 256];
        float4 bb = b4[tid + j * 256];
        float4 y = yv[j];
        y.x = (y.x - mu) * rs * g.x + bb.x;
        y.y = (y.y - mu) * rs * g.y + bb.y;
        y.z = (y.z - mu) * rs * g.z + bb.z;
        y.w = (y.w - mu) * rs * g.w + bb.w;
        out4[tid + j * 256] = y;
    }
}

// ---------------- launch ----------------
extern "C" void kernel_launch(void* const* d_in, const int* in_sizes, int n_in,
                              void* d_out, int out_size, void* d_ws, size_t ws_size,
                              hipStream_t stream) {
    const float* x     = (const float*)d_in[0];
    const float* Wq    = (const float*)d_in[1];
    const float* bq    = (const float*)d_in[2];
    const float* Wk    = (const float*)d_in[3];
    const float* bk    = (const float*)d_in[4];
    const float* Wv    = (const float*)d_in[5];
    const float* bv    = (const float*)d_in[6];
    const float* gamma = (const float*)d_in[7];
    const float* beta  = (const float*)d_in[8];
    float* out = (float*)d_out;

    char* ws = (char*)d_ws;
    const size_t wbt_bytes  = (size_t)NJ * C3 * DD * 2;        // 9,437,184
    const size_t bias_bytes = (size_t)NJ * C3 * 4;             // 73,728
    const size_t xb_bytes   = (size_t)NT * NJ * DD * 2;        // 100,663,296
    unsigned short* wbt = (unsigned short*)ws;
    float* bias = (float*)(ws + wbt_bytes);
    unsigned short* xb  = (unsigned short*)(ws + wbt_bytes + bias_bytes);
    unsigned short* qkv = (unsigned short*)(ws + wbt_bytes + bias_bytes + xb_bytes);

    // chunk tokens so qkv scratch fits in remaining ws
    const size_t fixed = wbt_bytes + bias_bytes + xb_bytes;
    size_t avail = (ws_size > fixed) ? ws_size - fixed : 0;
    int chunk = NT;
    while (chunk > BM && (size_t)chunk * NJ * C3 * 2 > avail) chunk >>= 1;

    const size_t wtotal = (size_t)NJ * C3 * DD;
    pack_w<<<dim3((unsigned)((wtotal + 255) / 256)), dim3(256), 0, stream>>>(Wq, Wk, Wv, wbt);
    pack_b<<<dim3((NJ * C3 + 255) / 256), dim3(256), 0, stream>>>(bq, bk, bv, bias);
    const size_t xtotal4 = (size_t)NT * NJ * DD / 4;
    pack_x<<<dim3((unsigned)((xtotal4 + 255) / 256)), dim3(256), 0, stream>>>(x, xb);

    for (int t0 = 0; t0 < NT; t0 += chunk) {
        int mbs = chunk / BM;
        gemm_qkv<<<dim3(6 * mbs * NJ), dim3(256), 0, stream>>>(xb, wbt, bias, qkv, t0, mbs);
        attn_ln<<<dim3(chunk), dim3(256), 0, stream>>>(qkv, x, gamma, beta, out, t0);
    }
}